// Round 1
// baseline (863.071 us; speedup 1.0000x reference)
//
#include <hip/hip_runtime.h>

// GeometryOptimalTransport: B=4, N=M=4096, C=128
// Sinkhorn (3 iters) over log_K(m,n) = -dist2/eps masked to -1e9, then
// attn-weighted gather of source feats.
//
// Faithful fp32 emulation of the reference, including the finite -1e9
// "NEG_INF" contamination semantics (fully-invalid rows get u=+1e9 exactly,
// which makes log_K+u == 0.0 in the v-update).

constexpr int   BB = 4;
constexpr int   NN = 4096;
constexpr int   MM = 4096;
constexpr int   CC = 128;
constexpr float kNegInf   = -1000000000.0f;
constexpr float kThresh2  = 0.04f;                 // 0.2^2 as fp32
constexpr float kNegInvEps = -(1.0f / 0.01000001f); // -(1/(EPSILON+1e-8))

__device__ inline float wave_reduce_max(float x) {
#pragma unroll
  for (int off = 32; off > 0; off >>= 1)
    x = fmaxf(x, __shfl_xor(x, off, 64));
  return x;
}
__device__ inline float wave_reduce_sum(float x) {
#pragma unroll
  for (int off = 32; off > 0; off >>= 1)
    x += __shfl_xor(x, off, 64);
  return x;
}

__global__ __launch_bounds__(256) void init_v_kernel(float* __restrict__ v) {
  int i = blockIdx.x * 256 + threadIdx.x;
  if (i < BB * NN) v[i] = 0.0f;
}

// u[b,m] = -logsumexp_n( logK(m,n) + v[b,n] ), one wave per (b,m)
__global__ __launch_bounds__(256) void u_update_kernel(
    const float* __restrict__ src_locs, const float* __restrict__ tgt_locs,
    const int* __restrict__ src_valid, const int* __restrict__ tgt_valid,
    const float* __restrict__ v, float* __restrict__ u)
{
  const int lane = threadIdx.x & 63;
  const int row  = blockIdx.x * 4 + (threadIdx.x >> 6);  // b*MM + m
  const int b    = row / MM;
  const float tx = tgt_locs[row * 2 + 0];
  const float ty = tgt_locs[row * 2 + 1];
  const bool  tv = tgt_valid[row] != 0;
  const float2* __restrict__ sl  = (const float2*)(src_locs + (size_t)b * NN * 2);
  const float*  __restrict__ vb  = v + (size_t)b * NN;
  const int*    __restrict__ svb = src_valid + (size_t)b * NN;

  // pass 1: row max of t = logK_masked + v
  float mx = -3.0e38f;
#pragma unroll 4
  for (int i = 0; i < NN / 64; ++i) {
    int n = i * 64 + lane;
    float2 s = sl[n];
    float dx = tx - s.x, dy = ty - s.y;
    float d2 = dx * dx + dy * dy;
    bool valid = (d2 < kThresh2) & tv & (svb[n] != 0);
    float t = (valid ? d2 * kNegInvEps : kNegInf) + vb[n];
    mx = fmaxf(mx, t);
  }
  mx = wave_reduce_max(mx);

  // pass 2: sum of exp(t - mx) over ALL n (invalid entries matter when
  // mx itself is ~-1e9: they contribute exp(0)=1 each — reference semantics)
  float s = 0.0f;
#pragma unroll 4
  for (int i = 0; i < NN / 64; ++i) {
    int n = i * 64 + lane;
    float2 sc = sl[n];
    float dx = tx - sc.x, dy = ty - sc.y;
    float d2 = dx * dx + dy * dy;
    bool valid = (d2 < kThresh2) & tv & (svb[n] != 0);
    float t = (valid ? d2 * kNegInvEps : kNegInf) + vb[n];
    s += __expf(t - mx);
  }
  s = wave_reduce_sum(s);
  if (lane == 0) u[row] = -(mx + __logf(s));
}

// v[b,n] = src_valid ? -logsumexp_m( logK(m,n) + u[b,m] ) : 0, one wave per (b,n)
__global__ __launch_bounds__(256) void v_update_kernel(
    const float* __restrict__ src_locs, const float* __restrict__ tgt_locs,
    const int* __restrict__ src_valid, const int* __restrict__ tgt_valid,
    const float* __restrict__ u, float* __restrict__ v)
{
  const int lane = threadIdx.x & 63;
  const int col  = blockIdx.x * 4 + (threadIdx.x >> 6);  // b*NN + n
  const int b    = col / NN;
  const float sx = src_locs[col * 2 + 0];
  const float sy = src_locs[col * 2 + 1];
  const bool  sv = src_valid[col] != 0;
  const float2* __restrict__ tl  = (const float2*)(tgt_locs + (size_t)b * MM * 2);
  const float*  __restrict__ ub  = u + (size_t)b * MM;
  const int*    __restrict__ tvb = tgt_valid + (size_t)b * MM;

  float mx = -3.0e38f;
#pragma unroll 4
  for (int i = 0; i < MM / 64; ++i) {
    int m = i * 64 + lane;
    float2 t2 = tl[m];
    float dx = t2.x - sx, dy = t2.y - sy;
    float d2 = dx * dx + dy * dy;
    bool valid = (d2 < kThresh2) & sv & (tvb[m] != 0);
    float t = (valid ? d2 * kNegInvEps : kNegInf) + ub[m];
    mx = fmaxf(mx, t);
  }
  mx = wave_reduce_max(mx);

  float s = 0.0f;
#pragma unroll 4
  for (int i = 0; i < MM / 64; ++i) {
    int m = i * 64 + lane;
    float2 t2 = tl[m];
    float dx = t2.x - sx, dy = t2.y - sy;
    float d2 = dx * dx + dy * dy;
    bool valid = (d2 < kThresh2) & sv & (tvb[m] != 0);
    float t = (valid ? d2 * kNegInvEps : kNegInf) + ub[m];
    s += __expf(t - mx);
  }
  s = wave_reduce_sum(s);
  if (lane == 0) v[col] = sv ? -(mx + __logf(s)) : 0.0f;
}

// out[b,m,:] = sum_n attn(m,n) * feats[b,n,:]; attn = exp(logK+u+v)*valid
// one block (256 threads) per (b,m); compact valid (n, attn) pairs in LDS,
// then gather coalesced 512B feat rows.
__global__ __launch_bounds__(256) void output_kernel(
    const float* __restrict__ src_locs, const float* __restrict__ tgt_locs,
    const int* __restrict__ src_valid, const int* __restrict__ tgt_valid,
    const float* __restrict__ u, const float* __restrict__ v,
    const float* __restrict__ feats, float* __restrict__ out)
{
  __shared__ float s_attn[NN];
  __shared__ int   s_idx[NN];
  __shared__ int   s_cnt;
  __shared__ float s_part[CC];

  const int row = blockIdx.x;            // b*MM + m
  const int b   = row / MM;
  const int tid = threadIdx.x;
  if (tid == 0) s_cnt = 0;
  __syncthreads();

  const float tx = tgt_locs[row * 2 + 0];
  const float ty = tgt_locs[row * 2 + 1];
  const bool  tv = tgt_valid[row] != 0;
  const float um = u[row];
  const float2* __restrict__ sl  = (const float2*)(src_locs + (size_t)b * NN * 2);
  const float*  __restrict__ vb  = v + (size_t)b * NN;
  const int*    __restrict__ svb = src_valid + (size_t)b * NN;

#pragma unroll 4
  for (int i = 0; i < NN / 256; ++i) {
    int n = i * 256 + tid;
    float2 s = sl[n];
    float dx = tx - s.x, dy = ty - s.y;
    float d2 = dx * dx + dy * dy;
    bool valid = (d2 < kThresh2) & tv & (svb[n] != 0);
    if (valid) {
      float a = __expf((d2 * kNegInvEps + um) + vb[n]);
      int p = atomicAdd(&s_cnt, 1);
      s_attn[p] = a;
      s_idx[p]  = n;
    }
  }
  __syncthreads();

  const int cnt = s_cnt;
  const int g = tid >> 7;        // 0 or 1: split entries even/odd
  const int c = tid & (CC - 1);
  const float* __restrict__ fb = feats + (size_t)b * NN * CC;
  float acc = 0.0f;
  for (int j = g; j < cnt; j += 2) {
    float a = s_attn[j];         // LDS broadcast (wave-uniform)
    int   n = s_idx[j];
    acc = fmaf(a, fb[(size_t)n * CC + c], acc);
  }
  if (g == 1) s_part[c] = acc;
  __syncthreads();
  if (g == 0) {
    float r = (cnt > 0) ? (acc + s_part[c]) : 0.0f;  // cnt>0 == has_source & tgt_valid
    out[(size_t)row * CC + c] = r;
  }
}

extern "C" void kernel_launch(void* const* d_in, const int* in_sizes, int n_in,
                              void* d_out, int out_size, void* d_ws, size_t ws_size,
                              hipStream_t stream) {
  const float* feats = (const float*)d_in[0];
  const float* sloc  = (const float*)d_in[1];
  const float* tloc  = (const float*)d_in[2];
  const int*   smask = (const int*)d_in[3];
  const int*   tmask = (const int*)d_in[4];
  float* out = (float*)d_out;

  float* u = (float*)d_ws;           // B*M floats
  float* v = u + (size_t)BB * MM;    // B*N floats

  init_v_kernel<<<(BB * NN + 255) / 256, 256, 0, stream>>>(v);
  for (int it = 0; it < 3; ++it) {
    u_update_kernel<<<BB * MM / 4, 256, 0, stream>>>(sloc, tloc, smask, tmask, v, u);
    v_update_kernel<<<BB * NN / 4, 256, 0, stream>>>(sloc, tloc, smask, tmask, u, v);
  }
  output_kernel<<<BB * MM, 256, 0, stream>>>(sloc, tloc, smask, tmask, u, v, feats, out);
}

// Round 2
// 323.365 us; speedup vs baseline: 2.6690x; 2.6690x over previous
//
#include <hip/hip_runtime.h>

// GeometryOptimalTransport: B=4, N=M=4096, C=128
// Sinkhorn (3 iters) over log_K(m,n) = -dist2/eps masked to -1e9, then
// attn-weighted gather of source feats.
//
// R2: validity is iteration-invariant -> precompute compacted neighbor lists
// (u16 indices, CAP=512) once; run all 6 lse updates + output on the ~3%
// dense lists. The finite NEG_INF=-1e9 contamination is closed-form:
//   - row with 0 valid entries => u = +1e9 EXACTLY (fp32 rounding: ulp(1e9)=64)
//   - such rows contribute exp(0 - mx) to EVERY column lse => per-batch count cc
//   - all other invalid entries underflow to exactly 0 in fp32.

constexpr int   BB = 4;
constexpr int   NN = 4096;
constexpr int   MM = 4096;
constexpr int   CC = 128;
constexpr int   CAP = 512;                          // max neighbors per row/col (est max ~330)
constexpr float kNegInf    = -1000000000.0f;
constexpr float kThresh2   = 0.04f;                 // 0.2^2
constexpr float kNegInvEps = -(1.0f / 0.01000001f); // -(1/(EPSILON+1e-8))

__device__ inline float wave_reduce_max(float x) {
#pragma unroll
  for (int off = 32; off > 0; off >>= 1)
    x = fmaxf(x, __shfl_xor(x, off, 64));
  return x;
}
__device__ inline float wave_reduce_sum(float x) {
#pragma unroll
  for (int off = 32; off > 0; off >>= 1)
    x += __shfl_xor(x, off, 64);
  return x;
}

// ---------------------------------------------------------------------------
// FAST PATH (needs ~34 MB workspace)
// ---------------------------------------------------------------------------

// zero v + empty-row counters, fold masks into locs (invalid -> far sentinel;
// DIFFERENT sentinels per side so two invalid points are never "close").
__global__ __launch_bounds__(256) void prep_kernel(
    const float* __restrict__ sloc, const float* __restrict__ tloc,
    const int* __restrict__ sm, const int* __restrict__ tm,
    float* __restrict__ v, int* __restrict__ ecnt,
    float2* __restrict__ slm, float2* __restrict__ tlm)
{
  int i = blockIdx.x * 256 + threadIdx.x;
  if (i < BB * NN) {
    v[i] = 0.0f;
    float2 s = ((const float2*)sloc)[i];
    slm[i] = sm[i] ? s : make_float2(1.0e9f, 1.0e9f);
    float2 t = ((const float2*)tloc)[i];
    tlm[i] = tm[i] ? t : make_float2(3.0e9f, 3.0e9f);
    if (i < BB) ecnt[i] = 0;
  }
}

// one wave per row: ballot-compact indices of valid partners (d2 < thresh).
// Generic over direction (N == M == 4096).
__global__ __launch_bounds__(256) void sweep_kernel(
    const float2* __restrict__ alocs,   // row-side masked locs [B*4096]
    const float2* __restrict__ blocs,   // partner-side masked locs [B*4096]
    unsigned short* __restrict__ lists, // [B*4096*CAP]
    int* __restrict__ cnts,             // [B*4096]
    int* __restrict__ ecnt)             // per-batch empty-row count, or null
{
  const int lane = threadIdx.x & 63;
  const int row  = blockIdx.x * 4 + (threadIdx.x >> 6);
  const int b    = row >> 12;
  const float2 a = alocs[row];
  const float2* __restrict__ bl = blocs + (size_t)b * 4096;
  unsigned short* __restrict__ lst = lists + (size_t)row * CAP;
  int cnt = 0;
#pragma unroll 4
  for (int i = 0; i < 4096 / 64; ++i) {
    int n = i * 64 + lane;
    float2 s = bl[n];
    float dx = a.x - s.x, dy = a.y - s.y;
    bool val = (dx * dx + dy * dy) < kThresh2;
    unsigned long long m = __ballot(val);
    if (val) {
      int off = cnt + __popcll(m & ((1ull << lane) - 1ull));
      if (off < CAP) lst[off] = (unsigned short)n;
    }
    cnt += __popcll(m);
  }
  if (lane == 0) {
    if (cnt > CAP) cnt = CAP;  // would corrupt results; est. max ~330, never hit
    cnts[row] = cnt;
    if (ecnt && cnt == 0) atomicAdd(&ecnt[b], 1);
  }
}

// u[row] = cnt ? -lse_j(logK_j + v[n_j]) : +1e9  (one wave per row)
__global__ __launch_bounds__(256) void lse_row_kernel(
    const float2* __restrict__ tlm, const float2* __restrict__ slm,
    const unsigned short* __restrict__ row_idx, const int* __restrict__ row_cnt,
    const float* __restrict__ v, float* __restrict__ u)
{
  const int lane = threadIdx.x & 63;
  const int row  = blockIdx.x * 4 + (threadIdx.x >> 6);
  const int cnt  = row_cnt[row];
  if (cnt == 0) { if (lane == 0) u[row] = 1.0e9f; return; }
  const int b = row >> 12;
  const float2 a = tlm[row];
  const float2* __restrict__ sl = slm + (size_t)b * NN;
  const float*  __restrict__ vb = v + (size_t)b * NN;
  const unsigned short* __restrict__ lst = row_idx + (size_t)row * CAP;

  float t[CAP / 64];
  float mx = -3.0e38f;
#pragma unroll
  for (int i = 0; i < CAP / 64; ++i) {
    int j = i * 64 + lane;
    float tv = -3.0e38f;
    if (j < cnt) {
      int n = lst[j];
      float2 s = sl[n];
      float dx = a.x - s.x, dy = a.y - s.y;
      tv = (dx * dx + dy * dy) * kNegInvEps + vb[n];
    }
    t[i] = tv;
    mx = fmaxf(mx, tv);
  }
  mx = wave_reduce_max(mx);
  float ssum = 0.0f;
#pragma unroll
  for (int i = 0; i < CAP / 64; ++i) ssum += __expf(t[i] - mx);
  ssum = wave_reduce_sum(ssum);
  if (lane == 0) u[row] = -(mx + __logf(ssum));
}

// v[col] = !sv ? 0 : -lse(valid terms + cc copies of t=0)   (one wave per col)
__global__ __launch_bounds__(256) void lse_col_kernel(
    const float2* __restrict__ slm, const float2* __restrict__ tlm,
    const unsigned short* __restrict__ col_idx, const int* __restrict__ col_cnt,
    const int* __restrict__ smask, const int* __restrict__ ecnt,
    const float* __restrict__ u, float* __restrict__ v)
{
  const int lane = threadIdx.x & 63;
  const int col  = blockIdx.x * 4 + (threadIdx.x >> 6);
  if (!smask[col]) { if (lane == 0) v[col] = 0.0f; return; }
  const int cnt = col_cnt[col];
  const int b   = col >> 12;
  const int cc  = ecnt[b];
  if (cnt == 0 && cc == 0) { if (lane == 0) v[col] = 1.0e9f; return; }
  const float2 a = slm[col];
  const float2* __restrict__ tl = tlm + (size_t)b * MM;
  const float*  __restrict__ ub = u + (size_t)b * MM;
  const unsigned short* __restrict__ lst = col_idx + (size_t)col * CAP;

  float t[CAP / 64];
  float mx = -3.0e38f;
#pragma unroll
  for (int i = 0; i < CAP / 64; ++i) {
    int j = i * 64 + lane;
    float tv = -3.0e38f;
    if (j < cnt) {
      int m = lst[j];
      float2 s = tl[m];
      float dx = a.x - s.x, dy = a.y - s.y;
      tv = (dx * dx + dy * dy) * kNegInvEps + ub[m];
    }
    t[i] = tv;
    mx = fmaxf(mx, tv);
  }
  mx = wave_reduce_max(mx);
  if (cc > 0) mx = fmaxf(mx, 0.0f);   // the cc contamination entries are t = 0.0 exactly
  float ssum = 0.0f;
#pragma unroll
  for (int i = 0; i < CAP / 64; ++i) ssum += __expf(t[i] - mx);
  ssum = wave_reduce_sum(ssum);
  if (lane == 0) v[col] = -(mx + __logf(ssum + (float)cc * __expf(0.0f - mx)));
}

// out[row,:] = sum_j attn_j * feats[n_j,:], one block per row, float4 gathers,
// 8 feat rows in flight (group g = tid>>5 handles entries j = g, g+8, ...).
__global__ __launch_bounds__(256) void output2_kernel(
    const float2* __restrict__ tlm, const float2* __restrict__ slm,
    const unsigned short* __restrict__ row_idx, const int* __restrict__ row_cnt,
    const float* __restrict__ u, const float* __restrict__ v,
    const float* __restrict__ feats, float* __restrict__ out)
{
  __shared__ float s_attn[CAP];
  __shared__ unsigned short s_id[CAP];
  __shared__ float4 s_red[256];

  const int row = blockIdx.x;
  const int tid = threadIdx.x;
  const int b   = row >> 12;
  const int cnt = row_cnt[row];
  float4* op = (float4*)(out + (size_t)row * CC);
  if (cnt == 0) {                      // covers !tgt_valid and !has_source
    if (tid < 32) op[tid] = make_float4(0.f, 0.f, 0.f, 0.f);
    return;
  }
  const float um = u[row];
  const float2 a = tlm[row];
  const float2* __restrict__ sl = slm + (size_t)b * NN;
  const float*  __restrict__ vb = v + (size_t)b * NN;
  const unsigned short* __restrict__ lst = row_idx + (size_t)row * CAP;

  for (int j = tid; j < cnt; j += 256) {
    int n = lst[j];
    float2 s = sl[n];
    float dx = a.x - s.x, dy = a.y - s.y;
    s_attn[j] = __expf((dx * dx + dy * dy) * kNegInvEps + um + vb[n]);
    s_id[j] = (unsigned short)n;
  }
  __syncthreads();

  const int g = tid >> 5, l = tid & 31;
  const float4* __restrict__ fb = (const float4*)(feats + (size_t)b * NN * CC);
  float4 acc = make_float4(0.f, 0.f, 0.f, 0.f);
  for (int j = g; j < cnt; j += 8) {
    float aw = s_attn[j];
    int   n  = s_id[j];
    float4 f = fb[(size_t)n * 32 + l];
    acc.x = fmaf(aw, f.x, acc.x);
    acc.y = fmaf(aw, f.y, acc.y);
    acc.z = fmaf(aw, f.z, acc.z);
    acc.w = fmaf(aw, f.w, acc.w);
  }
  s_red[tid] = acc;
  __syncthreads();
  if (tid < 32) {
    float4 r = s_red[tid];
#pragma unroll
    for (int gg = 1; gg < 8; ++gg) {
      float4 p = s_red[gg * 32 + tid];
      r.x += p.x; r.y += p.y; r.z += p.z; r.w += p.w;
    }
    op[tid] = r;
  }
}

// ---------------------------------------------------------------------------
// FALLBACK PATH (round-1 kernels, ~128 KB workspace) — used if ws too small
// ---------------------------------------------------------------------------

__global__ __launch_bounds__(256) void init_v_kernel(float* __restrict__ v) {
  int i = blockIdx.x * 256 + threadIdx.x;
  if (i < BB * NN) v[i] = 0.0f;
}

__global__ __launch_bounds__(256) void u_update_kernel(
    const float* __restrict__ src_locs, const float* __restrict__ tgt_locs,
    const int* __restrict__ src_valid, const int* __restrict__ tgt_valid,
    const float* __restrict__ v, float* __restrict__ u)
{
  const int lane = threadIdx.x & 63;
  const int row  = blockIdx.x * 4 + (threadIdx.x >> 6);
  const int b    = row / MM;
  const float tx = tgt_locs[row * 2 + 0];
  const float ty = tgt_locs[row * 2 + 1];
  const bool  tv = tgt_valid[row] != 0;
  const float2* __restrict__ sl  = (const float2*)(src_locs + (size_t)b * NN * 2);
  const float*  __restrict__ vb  = v + (size_t)b * NN;
  const int*    __restrict__ svb = src_valid + (size_t)b * NN;
  float mx = -3.0e38f;
#pragma unroll 4
  for (int i = 0; i < NN / 64; ++i) {
    int n = i * 64 + lane;
    float2 s = sl[n];
    float dx = tx - s.x, dy = ty - s.y;
    float d2 = dx * dx + dy * dy;
    bool valid = (d2 < kThresh2) & tv & (svb[n] != 0);
    float t = (valid ? d2 * kNegInvEps : kNegInf) + vb[n];
    mx = fmaxf(mx, t);
  }
  mx = wave_reduce_max(mx);
  float s = 0.0f;
#pragma unroll 4
  for (int i = 0; i < NN / 64; ++i) {
    int n = i * 64 + lane;
    float2 sc = sl[n];
    float dx = tx - sc.x, dy = ty - sc.y;
    float d2 = dx * dx + dy * dy;
    bool valid = (d2 < kThresh2) & tv & (svb[n] != 0);
    float t = (valid ? d2 * kNegInvEps : kNegInf) + vb[n];
    s += __expf(t - mx);
  }
  s = wave_reduce_sum(s);
  if (lane == 0) u[row] = -(mx + __logf(s));
}

__global__ __launch_bounds__(256) void v_update_kernel(
    const float* __restrict__ src_locs, const float* __restrict__ tgt_locs,
    const int* __restrict__ src_valid, const int* __restrict__ tgt_valid,
    const float* __restrict__ u, float* __restrict__ v)
{
  const int lane = threadIdx.x & 63;
  const int col  = blockIdx.x * 4 + (threadIdx.x >> 6);
  const int b    = col / NN;
  const float sx = src_locs[col * 2 + 0];
  const float sy = src_locs[col * 2 + 1];
  const bool  sv = src_valid[col] != 0;
  const float2* __restrict__ tl  = (const float2*)(tgt_locs + (size_t)b * MM * 2);
  const float*  __restrict__ ub  = u + (size_t)b * MM;
  const int*    __restrict__ tvb = tgt_valid + (size_t)b * MM;
  float mx = -3.0e38f;
#pragma unroll 4
  for (int i = 0; i < MM / 64; ++i) {
    int m = i * 64 + lane;
    float2 t2 = tl[m];
    float dx = t2.x - sx, dy = t2.y - sy;
    float d2 = dx * dx + dy * dy;
    bool valid = (d2 < kThresh2) & sv & (tvb[m] != 0);
    float t = (valid ? d2 * kNegInvEps : kNegInf) + ub[m];
    mx = fmaxf(mx, t);
  }
  mx = wave_reduce_max(mx);
  float s = 0.0f;
#pragma unroll 4
  for (int i = 0; i < MM / 64; ++i) {
    int m = i * 64 + lane;
    float2 t2 = tl[m];
    float dx = t2.x - sx, dy = t2.y - sy;
    float d2 = dx * dx + dy * dy;
    bool valid = (d2 < kThresh2) & sv & (tvb[m] != 0);
    float t = (valid ? d2 * kNegInvEps : kNegInf) + ub[m];
    s += __expf(t - mx);
  }
  s = wave_reduce_sum(s);
  if (lane == 0) v[col] = sv ? -(mx + __logf(s)) : 0.0f;
}

__global__ __launch_bounds__(256) void output_kernel(
    const float* __restrict__ src_locs, const float* __restrict__ tgt_locs,
    const int* __restrict__ src_valid, const int* __restrict__ tgt_valid,
    const float* __restrict__ u, const float* __restrict__ v,
    const float* __restrict__ feats, float* __restrict__ out)
{
  __shared__ float s_attn[NN];
  __shared__ int   s_idx[NN];
  __shared__ int   s_cnt;
  __shared__ float s_part[CC];
  const int row = blockIdx.x;
  const int b   = row / MM;
  const int tid = threadIdx.x;
  if (tid == 0) s_cnt = 0;
  __syncthreads();
  const float tx = tgt_locs[row * 2 + 0];
  const float ty = tgt_locs[row * 2 + 1];
  const bool  tv = tgt_valid[row] != 0;
  const float um = u[row];
  const float2* __restrict__ sl  = (const float2*)(src_locs + (size_t)b * NN * 2);
  const float*  __restrict__ vb  = v + (size_t)b * NN;
  const int*    __restrict__ svb = src_valid + (size_t)b * NN;
#pragma unroll 4
  for (int i = 0; i < NN / 256; ++i) {
    int n = i * 256 + tid;
    float2 s = sl[n];
    float dx = tx - s.x, dy = ty - s.y;
    float d2 = dx * dx + dy * dy;
    bool valid = (d2 < kThresh2) & tv & (svb[n] != 0);
    if (valid) {
      float a = __expf((d2 * kNegInvEps + um) + vb[n]);
      int p = atomicAdd(&s_cnt, 1);
      s_attn[p] = a;
      s_idx[p]  = n;
    }
  }
  __syncthreads();
  const int cnt = s_cnt;
  const int g = tid >> 7;
  const int c = tid & (CC - 1);
  const float* __restrict__ fb = feats + (size_t)b * NN * CC;
  float acc = 0.0f;
  for (int j = g; j < cnt; j += 2) {
    float a = s_attn[j];
    int   n = s_idx[j];
    acc = fmaf(a, fb[(size_t)n * CC + c], acc);
  }
  if (g == 1) s_part[c] = acc;
  __syncthreads();
  if (g == 0) {
    float r = (cnt > 0) ? (acc + s_part[c]) : 0.0f;
    out[(size_t)row * CC + c] = r;
  }
}

// ---------------------------------------------------------------------------

extern "C" void kernel_launch(void* const* d_in, const int* in_sizes, int n_in,
                              void* d_out, int out_size, void* d_ws, size_t ws_size,
                              hipStream_t stream) {
  const float* feats = (const float*)d_in[0];
  const float* sloc  = (const float*)d_in[1];
  const float* tloc  = (const float*)d_in[2];
  const int*   smask = (const int*)d_in[3];
  const int*   tmask = (const int*)d_in[4];
  float* out = (float*)d_out;

  // workspace layout (fast path)
  char* p = (char*)d_ws;
  float* u_   = (float*)p;            p += (size_t)BB * MM * 4;
  float* v_   = (float*)p;            p += (size_t)BB * NN * 4;
  int* row_cnt = (int*)p;             p += (size_t)BB * MM * 4;
  int* col_cnt = (int*)p;             p += (size_t)BB * NN * 4;
  int* ecnt    = (int*)p;             p += 256;
  float2* slm  = (float2*)p;          p += (size_t)BB * NN * 8;
  float2* tlm  = (float2*)p;          p += (size_t)BB * MM * 8;
  unsigned short* row_idx = (unsigned short*)p; p += (size_t)BB * MM * CAP * 2;
  unsigned short* col_idx = (unsigned short*)p; p += (size_t)BB * NN * CAP * 2;
  size_t required = (size_t)(p - (char*)d_ws);

  if (ws_size >= required) {
    prep_kernel<<<(BB * NN + 255) / 256, 256, 0, stream>>>(
        sloc, tloc, smask, tmask, v_, ecnt, slm, tlm);
    sweep_kernel<<<BB * MM / 4, 256, 0, stream>>>(tlm, slm, row_idx, row_cnt, ecnt);
    sweep_kernel<<<BB * NN / 4, 256, 0, stream>>>(slm, tlm, col_idx, col_cnt, nullptr);
    for (int it = 0; it < 3; ++it) {
      lse_row_kernel<<<BB * MM / 4, 256, 0, stream>>>(tlm, slm, row_idx, row_cnt, v_, u_);
      lse_col_kernel<<<BB * NN / 4, 256, 0, stream>>>(slm, tlm, col_idx, col_cnt,
                                                      smask, ecnt, u_, v_);
    }
    output2_kernel<<<BB * MM, 256, 0, stream>>>(tlm, slm, row_idx, row_cnt,
                                                u_, v_, feats, out);
  } else {
    // fallback: round-1 path (dense re-sweeps), needs only 128 KB
    float* u = (float*)d_ws;
    float* v = u + (size_t)BB * MM;
    init_v_kernel<<<(BB * NN + 255) / 256, 256, 0, stream>>>(v);
    for (int it = 0; it < 3; ++it) {
      u_update_kernel<<<BB * MM / 4, 256, 0, stream>>>(sloc, tloc, smask, tmask, v, u);
      v_update_kernel<<<BB * NN / 4, 256, 0, stream>>>(sloc, tloc, smask, tmask, u, v);
    }
    output_kernel<<<BB * MM, 256, 0, stream>>>(sloc, tloc, smask, tmask, u, v, feats, out);
  }
}

// Round 3
// 299.574 us; speedup vs baseline: 2.8810x; 1.0794x over previous
//
#include <hip/hip_runtime.h>

// GeometryOptimalTransport: B=4, N=M=4096, C=128
// Sinkhorn (3 iters) over log_K(m,n) = -dist2/eps masked to -1e9, then
// attn-weighted gather of source feats.
//
// R2: validity is iteration-invariant -> compact neighbor lists (u16, CAP=512)
// once; run all 6 lse updates + output on the ~3% dense lists. Finite
// NEG_INF=-1e9 contamination is closed-form:
//   - row with 0 valid entries => u = +1e9 EXACTLY (ulp(1e9)=64)
//   - such rows contribute exp(0 - mx) to EVERY column lse => per-batch count cc
//   - all other invalid entries underflow to exactly 0 in fp32.
// R3: sweep was latency-bound (VALUBusy 12%) on repeated global reads of the
// 32KB partner array. Stage it in LDS per block, use v_mbcnt for the ballot
// prefix, fuse both sweep directions into one dispatch.

constexpr int   BB = 4;
constexpr int   NN = 4096;
constexpr int   MM = 4096;
constexpr int   CC = 128;
constexpr int   CAP = 512;                          // max neighbors (est max ~330)
constexpr float kNegInf    = -1000000000.0f;
constexpr float kThresh2   = 0.04f;                 // 0.2^2
constexpr float kNegInvEps = -(1.0f / 0.01000001f); // -(1/(EPSILON+1e-8))

__device__ inline float wave_reduce_max(float x) {
#pragma unroll
  for (int off = 32; off > 0; off >>= 1)
    x = fmaxf(x, __shfl_xor(x, off, 64));
  return x;
}
__device__ inline float wave_reduce_sum(float x) {
#pragma unroll
  for (int off = 32; off > 0; off >>= 1)
    x += __shfl_xor(x, off, 64);
  return x;
}
__device__ inline int lane_prefix(unsigned long long m) {
  // popcount of mask bits strictly below this lane (v_mbcnt_lo + v_mbcnt_hi)
  return __builtin_amdgcn_mbcnt_hi((unsigned)(m >> 32),
         __builtin_amdgcn_mbcnt_lo((unsigned)m, 0));
}

// ---------------------------------------------------------------------------
// FAST PATH (needs ~34 MB workspace)
// ---------------------------------------------------------------------------

// zero v + empty-row counters, fold masks into locs (invalid -> far sentinel;
// DIFFERENT sentinels per side so two invalid points are never "close").
__global__ __launch_bounds__(256) void prep_kernel(
    const float* __restrict__ sloc, const float* __restrict__ tloc,
    const int* __restrict__ sm, const int* __restrict__ tm,
    float* __restrict__ v, int* __restrict__ ecnt,
    float2* __restrict__ slm, float2* __restrict__ tlm)
{
  int i = blockIdx.x * 256 + threadIdx.x;
  if (i < BB * NN) {
    v[i] = 0.0f;
    float2 s = ((const float2*)sloc)[i];
    slm[i] = sm[i] ? s : make_float2(1.0e9f, 1.0e9f);
    float2 t = ((const float2*)tloc)[i];
    tlm[i] = tm[i] ? t : make_float2(3.0e9f, 3.0e9f);
    if (i < BB) ecnt[i] = 0;
  }
}

// Fused row+col neighbor sweep. Blocks [0,4096): row side (a=tlm vs b=slm);
// blocks [4096,8192): col side (a=slm vs b=tlm). 4 rows per block, one wave
// each; the 32KB partner-loc array is staged in LDS once per block.
__global__ __launch_bounds__(256) void sweep2_kernel(
    const float2* __restrict__ slm, const float2* __restrict__ tlm,
    unsigned short* __restrict__ row_idx, int* __restrict__ row_cnt,
    unsigned short* __restrict__ col_idx, int* __restrict__ col_cnt,
    int* __restrict__ ecnt)
{
  __shared__ float2 s_b[4096];

  const bool is_row = blockIdx.x < (BB * MM / 4);
  const int  rbase  = (is_row ? blockIdx.x : blockIdx.x - BB * MM / 4) * 4;
  const int  b      = rbase >> 12;

  const float2* __restrict__ bl = (is_row ? slm : tlm) + (size_t)b * 4096;
  // stage partner locs: 2048 float4 loads spread over 256 threads
  {
    const float4* __restrict__ src4 = (const float4*)bl;
    float4* dst4 = (float4*)s_b;
#pragma unroll
    for (int i = 0; i < 8; ++i)
      dst4[i * 256 + threadIdx.x] = src4[i * 256 + threadIdx.x];
  }
  __syncthreads();

  const int lane = threadIdx.x & 63;
  const int row  = rbase + (threadIdx.x >> 6);
  const float2 a = (is_row ? tlm : slm)[row];
  unsigned short* __restrict__ lst =
      (is_row ? row_idx : col_idx) + (size_t)row * CAP;

  int cnt = 0;
#pragma unroll 8
  for (int i = 0; i < 4096 / 64; ++i) {
    int n = i * 64 + lane;
    float2 s = s_b[n];
    float dx = a.x - s.x, dy = a.y - s.y;
    float d2 = dx * dx + dy * dy;      // SAME expression as lse/output kernels
    bool val = d2 < kThresh2;
    unsigned long long m = __ballot(val);
    if (val) {
      int off = cnt + lane_prefix(m);
      if (off < CAP) lst[off] = (unsigned short)n;
    }
    cnt += __popcll(m);                // m is wave-uniform -> s_bcnt1_i32_b64
  }
  if (lane == 0) {
    if (cnt > CAP) cnt = CAP;          // est. max ~330, never hit
    if (is_row) {
      row_cnt[row] = cnt;
      if (cnt == 0) atomicAdd(&ecnt[b], 1);
    } else {
      col_cnt[row] = cnt;
    }
  }
}

// u[row] = cnt ? -lse_j(logK_j + v[n_j]) : +1e9  (one wave per row)
__global__ __launch_bounds__(256) void lse_row_kernel(
    const float2* __restrict__ tlm, const float2* __restrict__ slm,
    const unsigned short* __restrict__ row_idx, const int* __restrict__ row_cnt,
    const float* __restrict__ v, float* __restrict__ u)
{
  const int lane = threadIdx.x & 63;
  const int row  = blockIdx.x * 4 + (threadIdx.x >> 6);
  const int cnt  = row_cnt[row];
  if (cnt == 0) { if (lane == 0) u[row] = 1.0e9f; return; }
  const int b = row >> 12;
  const float2 a = tlm[row];
  const float2* __restrict__ sl = slm + (size_t)b * NN;
  const float*  __restrict__ vb = v + (size_t)b * NN;
  const unsigned short* __restrict__ lst = row_idx + (size_t)row * CAP;

  float t[CAP / 64];
  float mx = -3.0e38f;
#pragma unroll
  for (int i = 0; i < CAP / 64; ++i) {
    int j = i * 64 + lane;
    float tv = -3.0e38f;
    if (j < cnt) {
      int n = lst[j];
      float2 s = sl[n];
      float dx = a.x - s.x, dy = a.y - s.y;
      tv = (dx * dx + dy * dy) * kNegInvEps + vb[n];
    }
    t[i] = tv;
    mx = fmaxf(mx, tv);
  }
  mx = wave_reduce_max(mx);
  float ssum = 0.0f;
#pragma unroll
  for (int i = 0; i < CAP / 64; ++i) ssum += __expf(t[i] - mx);
  ssum = wave_reduce_sum(ssum);
  if (lane == 0) u[row] = -(mx + __logf(ssum));
}

// v[col] = !sv ? 0 : -lse(valid terms + cc copies of t=0)   (one wave per col)
__global__ __launch_bounds__(256) void lse_col_kernel(
    const float2* __restrict__ slm, const float2* __restrict__ tlm,
    const unsigned short* __restrict__ col_idx, const int* __restrict__ col_cnt,
    const int* __restrict__ smask, const int* __restrict__ ecnt,
    const float* __restrict__ u, float* __restrict__ v)
{
  const int lane = threadIdx.x & 63;
  const int col  = blockIdx.x * 4 + (threadIdx.x >> 6);
  if (!smask[col]) { if (lane == 0) v[col] = 0.0f; return; }
  const int cnt = col_cnt[col];
  const int b   = col >> 12;
  const int cc  = ecnt[b];
  if (cnt == 0 && cc == 0) { if (lane == 0) v[col] = 1.0e9f; return; }
  const float2 a = slm[col];
  const float2* __restrict__ tl = tlm + (size_t)b * MM;
  const float*  __restrict__ ub = u + (size_t)b * MM;
  const unsigned short* __restrict__ lst = col_idx + (size_t)col * CAP;

  float t[CAP / 64];
  float mx = -3.0e38f;
#pragma unroll
  for (int i = 0; i < CAP / 64; ++i) {
    int j = i * 64 + lane;
    float tv = -3.0e38f;
    if (j < cnt) {
      int m = lst[j];
      float2 s = tl[m];
      float dx = a.x - s.x, dy = a.y - s.y;
      tv = (dx * dx + dy * dy) * kNegInvEps + ub[m];
    }
    t[i] = tv;
    mx = fmaxf(mx, tv);
  }
  mx = wave_reduce_max(mx);
  if (cc > 0) mx = fmaxf(mx, 0.0f);   // contamination entries are t = 0.0 exactly
  float ssum = 0.0f;
#pragma unroll
  for (int i = 0; i < CAP / 64; ++i) ssum += __expf(t[i] - mx);
  ssum = wave_reduce_sum(ssum);
  if (lane == 0) v[col] = -(mx + __logf(ssum + (float)cc * __expf(0.0f - mx)));
}

// out[row,:] = sum_j attn_j * feats[n_j,:], one block per row, float4 gathers,
// 8 feat rows in flight (group g = tid>>5 handles entries j = g, g+8, ...).
__global__ __launch_bounds__(256) void output2_kernel(
    const float2* __restrict__ tlm, const float2* __restrict__ slm,
    const unsigned short* __restrict__ row_idx, const int* __restrict__ row_cnt,
    const float* __restrict__ u, const float* __restrict__ v,
    const float* __restrict__ feats, float* __restrict__ out)
{
  __shared__ float s_attn[CAP];
  __shared__ unsigned short s_id[CAP];
  __shared__ float4 s_red[256];

  const int row = blockIdx.x;
  const int tid = threadIdx.x;
  const int b   = row >> 12;
  const int cnt = row_cnt[row];
  float4* op = (float4*)(out + (size_t)row * CC);
  if (cnt == 0) {                      // covers !tgt_valid and !has_source
    if (tid < 32) op[tid] = make_float4(0.f, 0.f, 0.f, 0.f);
    return;
  }
  const float um = u[row];
  const float2 a = tlm[row];
  const float2* __restrict__ sl = slm + (size_t)b * NN;
  const float*  __restrict__ vb = v + (size_t)b * NN;
  const unsigned short* __restrict__ lst = row_idx + (size_t)row * CAP;

  for (int j = tid; j < cnt; j += 256) {
    int n = lst[j];
    float2 s = sl[n];
    float dx = a.x - s.x, dy = a.y - s.y;
    s_attn[j] = __expf((dx * dx + dy * dy) * kNegInvEps + um + vb[n]);
    s_id[j] = (unsigned short)n;
  }
  __syncthreads();

  const int g = tid >> 5, l = tid & 31;
  const float4* __restrict__ fb = (const float4*)(feats + (size_t)b * NN * CC);
  float4 acc = make_float4(0.f, 0.f, 0.f, 0.f);
  for (int j = g; j < cnt; j += 8) {
    float aw = s_attn[j];
    int   n  = s_id[j];
    float4 f = fb[(size_t)n * 32 + l];
    acc.x = fmaf(aw, f.x, acc.x);
    acc.y = fmaf(aw, f.y, acc.y);
    acc.z = fmaf(aw, f.z, acc.z);
    acc.w = fmaf(aw, f.w, acc.w);
  }
  s_red[tid] = acc;
  __syncthreads();
  if (tid < 32) {
    float4 r = s_red[tid];
#pragma unroll
    for (int gg = 1; gg < 8; ++gg) {
      float4 p = s_red[gg * 32 + tid];
      r.x += p.x; r.y += p.y; r.z += p.z; r.w += p.w;
    }
    op[tid] = r;
  }
}

// ---------------------------------------------------------------------------
// FALLBACK PATH (round-1 kernels, ~128 KB workspace) — used if ws too small
// ---------------------------------------------------------------------------

__global__ __launch_bounds__(256) void init_v_kernel(float* __restrict__ v) {
  int i = blockIdx.x * 256 + threadIdx.x;
  if (i < BB * NN) v[i] = 0.0f;
}

__global__ __launch_bounds__(256) void u_update_kernel(
    const float* __restrict__ src_locs, const float* __restrict__ tgt_locs,
    const int* __restrict__ src_valid, const int* __restrict__ tgt_valid,
    const float* __restrict__ v, float* __restrict__ u)
{
  const int lane = threadIdx.x & 63;
  const int row  = blockIdx.x * 4 + (threadIdx.x >> 6);
  const int b    = row / MM;
  const float tx = tgt_locs[row * 2 + 0];
  const float ty = tgt_locs[row * 2 + 1];
  const bool  tv = tgt_valid[row] != 0;
  const float2* __restrict__ sl  = (const float2*)(src_locs + (size_t)b * NN * 2);
  const float*  __restrict__ vb  = v + (size_t)b * NN;
  const int*    __restrict__ svb = src_valid + (size_t)b * NN;
  float mx = -3.0e38f;
#pragma unroll 4
  for (int i = 0; i < NN / 64; ++i) {
    int n = i * 64 + lane;
    float2 s = sl[n];
    float dx = tx - s.x, dy = ty - s.y;
    float d2 = dx * dx + dy * dy;
    bool valid = (d2 < kThresh2) & tv & (svb[n] != 0);
    float t = (valid ? d2 * kNegInvEps : kNegInf) + vb[n];
    mx = fmaxf(mx, t);
  }
  mx = wave_reduce_max(mx);
  float s = 0.0f;
#pragma unroll 4
  for (int i = 0; i < NN / 64; ++i) {
    int n = i * 64 + lane;
    float2 sc = sl[n];
    float dx = tx - sc.x, dy = ty - sc.y;
    float d2 = dx * dx + dy * dy;
    bool valid = (d2 < kThresh2) & tv & (svb[n] != 0);
    float t = (valid ? d2 * kNegInvEps : kNegInf) + vb[n];
    s += __expf(t - mx);
  }
  s = wave_reduce_sum(s);
  if (lane == 0) u[row] = -(mx + __logf(s));
}

__global__ __launch_bounds__(256) void v_update_kernel(
    const float* __restrict__ src_locs, const float* __restrict__ tgt_locs,
    const int* __restrict__ src_valid, const int* __restrict__ tgt_valid,
    const float* __restrict__ u, float* __restrict__ v)
{
  const int lane = threadIdx.x & 63;
  const int col  = blockIdx.x * 4 + (threadIdx.x >> 6);
  const int b    = col / NN;
  const float sx = src_locs[col * 2 + 0];
  const float sy = src_locs[col * 2 + 1];
  const bool  sv = src_valid[col] != 0;
  const float2* __restrict__ tl  = (const float2*)(tgt_locs + (size_t)b * MM * 2);
  const float*  __restrict__ ub  = u + (size_t)b * MM;
  const int*    __restrict__ tvb = tgt_valid + (size_t)b * MM;
  float mx = -3.0e38f;
#pragma unroll 4
  for (int i = 0; i < MM / 64; ++i) {
    int m = i * 64 + lane;
    float2 t2 = tl[m];
    float dx = t2.x - sx, dy = t2.y - sy;
    float d2 = dx * dx + dy * dy;
    bool valid = (d2 < kThresh2) & sv & (tvb[m] != 0);
    float t = (valid ? d2 * kNegInvEps : kNegInf) + ub[m];
    mx = fmaxf(mx, t);
  }
  mx = wave_reduce_max(mx);
  float s = 0.0f;
#pragma unroll 4
  for (int i = 0; i < MM / 64; ++i) {
    int m = i * 64 + lane;
    float2 t2 = tl[m];
    float dx = t2.x - sx, dy = t2.y - sy;
    float d2 = dx * dx + dy * dy;
    bool valid = (d2 < kThresh2) & sv & (tvb[m] != 0);
    float t = (valid ? d2 * kNegInvEps : kNegInf) + ub[m];
    s += __expf(t - mx);
  }
  s = wave_reduce_sum(s);
  if (lane == 0) v[col] = sv ? -(mx + __logf(s)) : 0.0f;
}

__global__ __launch_bounds__(256) void output_kernel(
    const float* __restrict__ src_locs, const float* __restrict__ tgt_locs,
    const int* __restrict__ src_valid, const int* __restrict__ tgt_valid,
    const float* __restrict__ u, const float* __restrict__ v,
    const float* __restrict__ feats, float* __restrict__ out)
{
  __shared__ float s_attn[NN];
  __shared__ int   s_idx[NN];
  __shared__ int   s_cnt;
  __shared__ float s_part[CC];
  const int row = blockIdx.x;
  const int b   = row / MM;
  const int tid = threadIdx.x;
  if (tid == 0) s_cnt = 0;
  __syncthreads();
  const float tx = tgt_locs[row * 2 + 0];
  const float ty = tgt_locs[row * 2 + 1];
  const bool  tv = tgt_valid[row] != 0;
  const float um = u[row];
  const float2* __restrict__ sl  = (const float2*)(src_locs + (size_t)b * NN * 2);
  const float*  __restrict__ vb  = v + (size_t)b * NN;
  const int*    __restrict__ svb = src_valid + (size_t)b * NN;
#pragma unroll 4
  for (int i = 0; i < NN / 256; ++i) {
    int n = i * 256 + tid;
    float2 s = sl[n];
    float dx = tx - s.x, dy = ty - s.y;
    float d2 = dx * dx + dy * dy;
    bool valid = (d2 < kThresh2) & tv & (svb[n] != 0);
    if (valid) {
      float a = __expf((d2 * kNegInvEps + um) + vb[n]);
      int p = atomicAdd(&s_cnt, 1);
      s_attn[p] = a;
      s_idx[p]  = n;
    }
  }
  __syncthreads();
  const int cnt = s_cnt;
  const int g = tid >> 7;
  const int c = tid & (CC - 1);
  const float* __restrict__ fb = feats + (size_t)b * NN * CC;
  float acc = 0.0f;
  for (int j = g; j < cnt; j += 2) {
    float a = s_attn[j];
    int   n = s_idx[j];
    acc = fmaf(a, fb[(size_t)n * CC + c], acc);
  }
  if (g == 1) s_part[c] = acc;
  __syncthreads();
  if (g == 0) {
    float r = (cnt > 0) ? (acc + s_part[c]) : 0.0f;
    out[(size_t)row * CC + c] = r;
  }
}

// ---------------------------------------------------------------------------

extern "C" void kernel_launch(void* const* d_in, const int* in_sizes, int n_in,
                              void* d_out, int out_size, void* d_ws, size_t ws_size,
                              hipStream_t stream) {
  const float* feats = (const float*)d_in[0];
  const float* sloc  = (const float*)d_in[1];
  const float* tloc  = (const float*)d_in[2];
  const int*   smask = (const int*)d_in[3];
  const int*   tmask = (const int*)d_in[4];
  float* out = (float*)d_out;

  // workspace layout (fast path)
  char* p = (char*)d_ws;
  float* u_   = (float*)p;            p += (size_t)BB * MM * 4;
  float* v_   = (float*)p;            p += (size_t)BB * NN * 4;
  int* row_cnt = (int*)p;             p += (size_t)BB * MM * 4;
  int* col_cnt = (int*)p;             p += (size_t)BB * NN * 4;
  int* ecnt    = (int*)p;             p += 256;
  float2* slm  = (float2*)p;          p += (size_t)BB * NN * 8;
  float2* tlm  = (float2*)p;          p += (size_t)BB * MM * 8;
  unsigned short* row_idx = (unsigned short*)p; p += (size_t)BB * MM * CAP * 2;
  unsigned short* col_idx = (unsigned short*)p; p += (size_t)BB * NN * CAP * 2;
  size_t required = (size_t)(p - (char*)d_ws);

  if (ws_size >= required) {
    prep_kernel<<<(BB * NN + 255) / 256, 256, 0, stream>>>(
        sloc, tloc, smask, tmask, v_, ecnt, slm, tlm);
    sweep2_kernel<<<2 * BB * MM / 4, 256, 0, stream>>>(
        slm, tlm, row_idx, row_cnt, col_idx, col_cnt, ecnt);
    for (int it = 0; it < 3; ++it) {
      lse_row_kernel<<<BB * MM / 4, 256, 0, stream>>>(tlm, slm, row_idx, row_cnt, v_, u_);
      lse_col_kernel<<<BB * NN / 4, 256, 0, stream>>>(slm, tlm, col_idx, col_cnt,
                                                      smask, ecnt, u_, v_);
    }
    output2_kernel<<<BB * MM, 256, 0, stream>>>(tlm, slm, row_idx, row_cnt,
                                                u_, v_, feats, out);
  } else {
    // fallback: round-1 path (dense re-sweeps), needs only 128 KB
    float* u = (float*)d_ws;
    float* v = u + (size_t)BB * MM;
    init_v_kernel<<<(BB * NN + 255) / 256, 256, 0, stream>>>(v);
    for (int it = 0; it < 3; ++it) {
      u_update_kernel<<<BB * MM / 4, 256, 0, stream>>>(sloc, tloc, smask, tmask, v, u);
      v_update_kernel<<<BB * NN / 4, 256, 0, stream>>>(sloc, tloc, smask, tmask, u, v);
    }
    output_kernel<<<BB * MM, 256, 0, stream>>>(sloc, tloc, smask, tmask, u, v, feats, out);
  }
}

// Round 4
// 290.264 us; speedup vs baseline: 2.9734x; 1.0321x over previous
//
#include <hip/hip_runtime.h>

// GeometryOptimalTransport: B=4, N=M=4096, C=128
// Sinkhorn (3 iters) over log_K(m,n) = -dist2/eps masked to -1e9, then
// attn-weighted gather of source feats.
//
// R2: validity is iteration-invariant -> compact neighbor lists (u16, CAP=512)
// once; run all 6 lse updates + output on the ~3% dense lists. Finite
// NEG_INF=-1e9 contamination is closed-form:
//   - row with 0 valid entries => u = +1e9 EXACTLY (ulp(1e9)=64)
//   - such rows contribute exp(0 - mx) to EVERY column lse => per-batch count cc
//   - all other invalid entries underflow to exactly 0 in fp32.
// R4: sweep rebuilt as bitmask-then-compact. Inner loop is pure independent
// VALU (cmp+cndmask+or into per-lane 64-bit masks), no ballot/store/scalar
// chain; compaction (scan + ctz-extract into LDS + one uint4 flush) happens
// once per row. No LDS staging -> 4KB/block -> full occupancy.

constexpr int   BB = 4;
constexpr int   NN = 4096;
constexpr int   MM = 4096;
constexpr int   CC = 128;
constexpr int   CAP = 512;                          // max neighbors (est max ~330)
constexpr float kNegInf    = -1000000000.0f;
constexpr float kThresh2   = 0.04f;                 // 0.2^2
constexpr float kNegInvEps = -(1.0f / 0.01000001f); // -(1/(EPSILON+1e-8))

__device__ inline float wave_reduce_max(float x) {
#pragma unroll
  for (int off = 32; off > 0; off >>= 1)
    x = fmaxf(x, __shfl_xor(x, off, 64));
  return x;
}
__device__ inline float wave_reduce_sum(float x) {
#pragma unroll
  for (int off = 32; off > 0; off >>= 1)
    x += __shfl_xor(x, off, 64);
  return x;
}

// ---------------------------------------------------------------------------
// FAST PATH (needs ~34 MB workspace)
// ---------------------------------------------------------------------------

// zero v + empty-row counters, fold masks into locs (invalid -> far sentinel;
// DIFFERENT sentinels per side so two invalid points are never "close").
__global__ __launch_bounds__(256) void prep_kernel(
    const float* __restrict__ sloc, const float* __restrict__ tloc,
    const int* __restrict__ sm, const int* __restrict__ tm,
    float* __restrict__ v, int* __restrict__ ecnt,
    float2* __restrict__ slm, float2* __restrict__ tlm)
{
  int i = blockIdx.x * 256 + threadIdx.x;
  if (i < BB * NN) {
    v[i] = 0.0f;
    float2 s = ((const float2*)sloc)[i];
    slm[i] = sm[i] ? s : make_float2(1.0e9f, 1.0e9f);
    float2 t = ((const float2*)tloc)[i];
    tlm[i] = tm[i] ? t : make_float2(3.0e9f, 3.0e9f);
    if (i < BB) ecnt[i] = 0;
  }
}

// Fused row+col neighbor sweep, bitmask-then-compact.
// Blocks [0,4096): row side (a=tlm vs partners=slm);
// blocks [4096,8192): col side (a=slm vs partners=tlm).
// 4 waves/block, one row per wave. Lane L, iter i tests partners
// i*128+2L and i*128+2L+1 (one float4). Bit b=2i+p of lane L's 64-bit mask.
__global__ __launch_bounds__(256) void sweep3_kernel(
    const float2* __restrict__ slm, const float2* __restrict__ tlm,
    unsigned short* __restrict__ row_idx, int* __restrict__ row_cnt,
    unsigned short* __restrict__ col_idx, int* __restrict__ col_cnt,
    int* __restrict__ ecnt)
{
  __shared__ unsigned short s_list[4 * CAP];

  const bool is_row = blockIdx.x < (BB * MM / 4);
  const int  rbase  = (is_row ? blockIdx.x : blockIdx.x - BB * MM / 4) * 4;
  const int  b      = rbase >> 12;
  const int  lane   = threadIdx.x & 63;
  const int  wid    = threadIdx.x >> 6;
  const int  row    = rbase + wid;

  const float2 a = (is_row ? tlm : slm)[row];
  const float4* __restrict__ bl4 =
      (const float4*)((is_row ? slm : tlm) + (size_t)b * 4096);
  unsigned short* __restrict__ lst =
      (is_row ? row_idx : col_idx) + (size_t)row * CAP;

  // phase 1: per-lane 64-bit validity mask, pure independent VALU
  unsigned w[4];
#pragma unroll
  for (int g = 0; g < 4; ++g) {
    unsigned acc = 0;
#pragma unroll
    for (int k = 0; k < 8; ++k) {
      int i = g * 8 + k;
      float4 q = bl4[i * 64 + lane];
      float dx0 = a.x - q.x, dy0 = a.y - q.y;
      float dx1 = a.x - q.z, dy1 = a.y - q.w;
      float d0 = dx0 * dx0 + dy0 * dy0;
      float d1 = dx1 * dx1 + dy1 * dy1;
      acc |= (d0 < kThresh2) ? (1u << (2 * k)) : 0u;
      acc |= (d1 < kThresh2) ? (1u << (2 * k + 1)) : 0u;
    }
    w[g] = acc;
  }
  unsigned long long msk =
      (unsigned long long)(w[0] | (w[1] << 16)) |
      ((unsigned long long)(w[2] | (w[3] << 16)) << 32);

  // phase 2: compact. inclusive shfl-scan of per-lane counts -> offsets.
  int c = __popcll(msk);
  int scan = c;
#pragma unroll
  for (int off = 1; off < 64; off <<= 1) {
    int y = __shfl_up(scan, off, 64);
    if (lane >= off) scan += y;
  }
  int total = __shfl(scan, 63, 64);
  int off = scan - c;

  // serial per-lane extraction (avg ~4 bits/lane) into per-wave LDS buffer
  unsigned short* buf = s_list + wid * CAP;
  unsigned long long m = msk;
  while (m) {
    int bit = (int)__builtin_ctzll(m);
    m &= m - 1;
    int n = ((bit >> 1) << 7) + 2 * lane + (bit & 1);  // (b/2)*128 + 2L + (b&1)
    if (off < CAP) buf[off] = (unsigned short)n;
    ++off;
  }

  // coalesced flush: whole CAP buffer (1KB) = 64 lanes x 16B, garbage tail ok
  {
    const uint4* lsrc = (const uint4*)buf;
    ((uint4*)lst)[lane] = lsrc[lane];
  }
  if (lane == 0) {
    int cnt = total > CAP ? CAP : total;  // est. max ~330, never hit
    if (is_row) {
      row_cnt[row] = cnt;
      if (cnt == 0) atomicAdd(&ecnt[b], 1);
    } else {
      col_cnt[row] = cnt;
    }
  }
}

// u[row] = cnt ? -lse_j(logK_j + v[n_j]) : +1e9  (one wave per row)
__global__ __launch_bounds__(256) void lse_row_kernel(
    const float2* __restrict__ tlm, const float2* __restrict__ slm,
    const unsigned short* __restrict__ row_idx, const int* __restrict__ row_cnt,
    const float* __restrict__ v, float* __restrict__ u)
{
  const int lane = threadIdx.x & 63;
  const int row  = blockIdx.x * 4 + (threadIdx.x >> 6);
  const int cnt  = row_cnt[row];
  if (cnt == 0) { if (lane == 0) u[row] = 1.0e9f; return; }
  const int b = row >> 12;
  const float2 a = tlm[row];
  const float2* __restrict__ sl = slm + (size_t)b * NN;
  const float*  __restrict__ vb = v + (size_t)b * NN;
  const unsigned short* __restrict__ lst = row_idx + (size_t)row * CAP;

  float t[CAP / 64];
  float mx = -3.0e38f;
#pragma unroll
  for (int i = 0; i < CAP / 64; ++i) {
    int j = i * 64 + lane;
    float tv = -3.0e38f;
    if (j < cnt) {
      int n = lst[j];
      float2 s = sl[n];
      float dx = a.x - s.x, dy = a.y - s.y;
      tv = (dx * dx + dy * dy) * kNegInvEps + vb[n];
    }
    t[i] = tv;
    mx = fmaxf(mx, tv);
  }
  mx = wave_reduce_max(mx);
  float ssum = 0.0f;
#pragma unroll
  for (int i = 0; i < CAP / 64; ++i) ssum += __expf(t[i] - mx);
  ssum = wave_reduce_sum(ssum);
  if (lane == 0) u[row] = -(mx + __logf(ssum));
}

// v[col] = !sv ? 0 : -lse(valid terms + cc copies of t=0)   (one wave per col)
__global__ __launch_bounds__(256) void lse_col_kernel(
    const float2* __restrict__ slm, const float2* __restrict__ tlm,
    const unsigned short* __restrict__ col_idx, const int* __restrict__ col_cnt,
    const int* __restrict__ smask, const int* __restrict__ ecnt,
    const float* __restrict__ u, float* __restrict__ v)
{
  const int lane = threadIdx.x & 63;
  const int col  = blockIdx.x * 4 + (threadIdx.x >> 6);
  if (!smask[col]) { if (lane == 0) v[col] = 0.0f; return; }
  const int cnt = col_cnt[col];
  const int b   = col >> 12;
  const int cc  = ecnt[b];
  if (cnt == 0 && cc == 0) { if (lane == 0) v[col] = 1.0e9f; return; }
  const float2 a = slm[col];
  const float2* __restrict__ tl = tlm + (size_t)b * MM;
  const float*  __restrict__ ub = u + (size_t)b * MM;
  const unsigned short* __restrict__ lst = col_idx + (size_t)col * CAP;

  float t[CAP / 64];
  float mx = -3.0e38f;
#pragma unroll
  for (int i = 0; i < CAP / 64; ++i) {
    int j = i * 64 + lane;
    float tv = -3.0e38f;
    if (j < cnt) {
      int m = lst[j];
      float2 s = tl[m];
      float dx = a.x - s.x, dy = a.y - s.y;
      tv = (dx * dx + dy * dy) * kNegInvEps + ub[m];
    }
    t[i] = tv;
    mx = fmaxf(mx, tv);
  }
  mx = wave_reduce_max(mx);
  if (cc > 0) mx = fmaxf(mx, 0.0f);   // contamination entries are t = 0.0 exactly
  float ssum = 0.0f;
#pragma unroll
  for (int i = 0; i < CAP / 64; ++i) ssum += __expf(t[i] - mx);
  ssum = wave_reduce_sum(ssum);
  if (lane == 0) v[col] = -(mx + __logf(ssum + (float)cc * __expf(0.0f - mx)));
}

// out[row,:] = sum_j attn_j * feats[n_j,:], one block per row, float4 gathers,
// 8 feat rows in flight (group g = tid>>5 handles entries j = g, g+8, ...).
__global__ __launch_bounds__(256) void output2_kernel(
    const float2* __restrict__ tlm, const float2* __restrict__ slm,
    const unsigned short* __restrict__ row_idx, const int* __restrict__ row_cnt,
    const float* __restrict__ u, const float* __restrict__ v,
    const float* __restrict__ feats, float* __restrict__ out)
{
  __shared__ float s_attn[CAP];
  __shared__ unsigned short s_id[CAP];
  __shared__ float4 s_red[256];

  const int row = blockIdx.x;
  const int tid = threadIdx.x;
  const int b   = row >> 12;
  const int cnt = row_cnt[row];
  float4* op = (float4*)(out + (size_t)row * CC);
  if (cnt == 0) {                      // covers !tgt_valid and !has_source
    if (tid < 32) op[tid] = make_float4(0.f, 0.f, 0.f, 0.f);
    return;
  }
  const float um = u[row];
  const float2 a = tlm[row];
  const float2* __restrict__ sl = slm + (size_t)b * NN;
  const float*  __restrict__ vb = v + (size_t)b * NN;
  const unsigned short* __restrict__ lst = row_idx + (size_t)row * CAP;

  for (int j = tid; j < cnt; j += 256) {
    int n = lst[j];
    float2 s = sl[n];
    float dx = a.x - s.x, dy = a.y - s.y;
    s_attn[j] = __expf((dx * dx + dy * dy) * kNegInvEps + um + vb[n]);
    s_id[j] = (unsigned short)n;
  }
  __syncthreads();

  const int g = tid >> 5, l = tid & 31;
  const float4* __restrict__ fb = (const float4*)(feats + (size_t)b * NN * CC);
  float4 acc = make_float4(0.f, 0.f, 0.f, 0.f);
  for (int j = g; j < cnt; j += 8) {
    float aw = s_attn[j];
    int   n  = s_id[j];
    float4 f = fb[(size_t)n * 32 + l];
    acc.x = fmaf(aw, f.x, acc.x);
    acc.y = fmaf(aw, f.y, acc.y);
    acc.z = fmaf(aw, f.z, acc.z);
    acc.w = fmaf(aw, f.w, acc.w);
  }
  s_red[tid] = acc;
  __syncthreads();
  if (tid < 32) {
    float4 r = s_red[tid];
#pragma unroll
    for (int gg = 1; gg < 8; ++gg) {
      float4 p = s_red[gg * 32 + tid];
      r.x += p.x; r.y += p.y; r.z += p.z; r.w += p.w;
    }
    op[tid] = r;
  }
}

// ---------------------------------------------------------------------------
// FALLBACK PATH (round-1 kernels, ~128 KB workspace) — used if ws too small
// ---------------------------------------------------------------------------

__global__ __launch_bounds__(256) void init_v_kernel(float* __restrict__ v) {
  int i = blockIdx.x * 256 + threadIdx.x;
  if (i < BB * NN) v[i] = 0.0f;
}

__global__ __launch_bounds__(256) void u_update_kernel(
    const float* __restrict__ src_locs, const float* __restrict__ tgt_locs,
    const int* __restrict__ src_valid, const int* __restrict__ tgt_valid,
    const float* __restrict__ v, float* __restrict__ u)
{
  const int lane = threadIdx.x & 63;
  const int row  = blockIdx.x * 4 + (threadIdx.x >> 6);
  const int b    = row / MM;
  const float tx = tgt_locs[row * 2 + 0];
  const float ty = tgt_locs[row * 2 + 1];
  const bool  tv = tgt_valid[row] != 0;
  const float2* __restrict__ sl  = (const float2*)(src_locs + (size_t)b * NN * 2);
  const float*  __restrict__ vb  = v + (size_t)b * NN;
  const int*    __restrict__ svb = src_valid + (size_t)b * NN;
  float mx = -3.0e38f;
#pragma unroll 4
  for (int i = 0; i < NN / 64; ++i) {
    int n = i * 64 + lane;
    float2 s = sl[n];
    float dx = tx - s.x, dy = ty - s.y;
    float d2 = dx * dx + dy * dy;
    bool valid = (d2 < kThresh2) & tv & (svb[n] != 0);
    float t = (valid ? d2 * kNegInvEps : kNegInf) + vb[n];
    mx = fmaxf(mx, t);
  }
  mx = wave_reduce_max(mx);
  float s = 0.0f;
#pragma unroll 4
  for (int i = 0; i < NN / 64; ++i) {
    int n = i * 64 + lane;
    float2 sc = sl[n];
    float dx = tx - sc.x, dy = ty - sc.y;
    float d2 = dx * dx + dy * dy;
    bool valid = (d2 < kThresh2) & tv & (svb[n] != 0);
    float t = (valid ? d2 * kNegInvEps : kNegInf) + vb[n];
    s += __expf(t - mx);
  }
  s = wave_reduce_sum(s);
  if (lane == 0) u[row] = -(mx + __logf(s));
}

__global__ __launch_bounds__(256) void v_update_kernel(
    const float* __restrict__ src_locs, const float* __restrict__ tgt_locs,
    const int* __restrict__ src_valid, const int* __restrict__ tgt_valid,
    const float* __restrict__ u, float* __restrict__ v)
{
  const int lane = threadIdx.x & 63;
  const int col  = blockIdx.x * 4 + (threadIdx.x >> 6);
  const int b    = col / NN;
  const float sx = src_locs[col * 2 + 0];
  const float sy = src_locs[col * 2 + 1];
  const bool  sv = src_valid[col] != 0;
  const float2* __restrict__ tl  = (const float2*)(tgt_locs + (size_t)b * MM * 2);
  const float*  __restrict__ ub  = u + (size_t)b * MM;
  const int*    __restrict__ tvb = tgt_valid + (size_t)b * MM;
  float mx = -3.0e38f;
#pragma unroll 4
  for (int i = 0; i < MM / 64; ++i) {
    int m = i * 64 + lane;
    float2 t2 = tl[m];
    float dx = t2.x - sx, dy = t2.y - sy;
    float d2 = dx * dx + dy * dy;
    bool valid = (d2 < kThresh2) & sv & (tvb[m] != 0);
    float t = (valid ? d2 * kNegInvEps : kNegInf) + ub[m];
    mx = fmaxf(mx, t);
  }
  mx = wave_reduce_max(mx);
  float s = 0.0f;
#pragma unroll 4
  for (int i = 0; i < MM / 64; ++i) {
    int m = i * 64 + lane;
    float2 t2 = tl[m];
    float dx = t2.x - sx, dy = t2.y - sy;
    float d2 = dx * dx + dy * dy;
    bool valid = (d2 < kThresh2) & sv & (tvb[m] != 0);
    float t = (valid ? d2 * kNegInvEps : kNegInf) + ub[m];
    s += __expf(t - mx);
  }
  s = wave_reduce_sum(s);
  if (lane == 0) v[col] = sv ? -(mx + __logf(s)) : 0.0f;
}

__global__ __launch_bounds__(256) void output_kernel(
    const float* __restrict__ src_locs, const float* __restrict__ tgt_locs,
    const int* __restrict__ src_valid, const int* __restrict__ tgt_valid,
    const float* __restrict__ u, const float* __restrict__ v,
    const float* __restrict__ feats, float* __restrict__ out)
{
  __shared__ float s_attn[NN];
  __shared__ int   s_idx[NN];
  __shared__ int   s_cnt;
  __shared__ float s_part[CC];
  const int row = blockIdx.x;
  const int b   = row / MM;
  const int tid = threadIdx.x;
  if (tid == 0) s_cnt = 0;
  __syncthreads();
  const float tx = tgt_locs[row * 2 + 0];
  const float ty = tgt_locs[row * 2 + 1];
  const bool  tv = tgt_valid[row] != 0;
  const float um = u[row];
  const float2* __restrict__ sl  = (const float2*)(src_locs + (size_t)b * NN * 2);
  const float*  __restrict__ vb  = v + (size_t)b * NN;
  const int*    __restrict__ svb = src_valid + (size_t)b * NN;
#pragma unroll 4
  for (int i = 0; i < NN / 256; ++i) {
    int n = i * 256 + tid;
    float2 s = sl[n];
    float dx = tx - s.x, dy = ty - s.y;
    float d2 = dx * dx + dy * dy;
    bool valid = (d2 < kThresh2) & tv & (svb[n] != 0);
    if (valid) {
      float a = __expf((d2 * kNegInvEps + um) + vb[n]);
      int p = atomicAdd(&s_cnt, 1);
      s_attn[p] = a;
      s_idx[p]  = n;
    }
  }
  __syncthreads();
  const int cnt = s_cnt;
  const int g = tid >> 7;
  const int c = tid & (CC - 1);
  const float* __restrict__ fb = feats + (size_t)b * NN * CC;
  float acc = 0.0f;
  for (int j = g; j < cnt; j += 2) {
    float a = s_attn[j];
    int   n = s_idx[j];
    acc = fmaf(a, fb[(size_t)n * CC + c], acc);
  }
  if (g == 1) s_part[c] = acc;
  __syncthreads();
  if (g == 0) {
    float r = (cnt > 0) ? (acc + s_part[c]) : 0.0f;
    out[(size_t)row * CC + c] = r;
  }
}

// ---------------------------------------------------------------------------

extern "C" void kernel_launch(void* const* d_in, const int* in_sizes, int n_in,
                              void* d_out, int out_size, void* d_ws, size_t ws_size,
                              hipStream_t stream) {
  const float* feats = (const float*)d_in[0];
  const float* sloc  = (const float*)d_in[1];
  const float* tloc  = (const float*)d_in[2];
  const int*   smask = (const int*)d_in[3];
  const int*   tmask = (const int*)d_in[4];
  float* out = (float*)d_out;

  // workspace layout (fast path)
  char* p = (char*)d_ws;
  float* u_   = (float*)p;            p += (size_t)BB * MM * 4;
  float* v_   = (float*)p;            p += (size_t)BB * NN * 4;
  int* row_cnt = (int*)p;             p += (size_t)BB * MM * 4;
  int* col_cnt = (int*)p;             p += (size_t)BB * NN * 4;
  int* ecnt    = (int*)p;             p += 256;
  float2* slm  = (float2*)p;          p += (size_t)BB * NN * 8;
  float2* tlm  = (float2*)p;          p += (size_t)BB * MM * 8;
  unsigned short* row_idx = (unsigned short*)p; p += (size_t)BB * MM * CAP * 2;
  unsigned short* col_idx = (unsigned short*)p; p += (size_t)BB * NN * CAP * 2;
  size_t required = (size_t)(p - (char*)d_ws);

  if (ws_size >= required) {
    prep_kernel<<<(BB * NN + 255) / 256, 256, 0, stream>>>(
        sloc, tloc, smask, tmask, v_, ecnt, slm, tlm);
    sweep3_kernel<<<2 * BB * MM / 4, 256, 0, stream>>>(
        slm, tlm, row_idx, row_cnt, col_idx, col_cnt, ecnt);
    for (int it = 0; it < 3; ++it) {
      lse_row_kernel<<<BB * MM / 4, 256, 0, stream>>>(tlm, slm, row_idx, row_cnt, v_, u_);
      lse_col_kernel<<<BB * NN / 4, 256, 0, stream>>>(slm, tlm, col_idx, col_cnt,
                                                      smask, ecnt, u_, v_);
    }
    output2_kernel<<<BB * MM, 256, 0, stream>>>(tlm, slm, row_idx, row_cnt,
                                                u_, v_, feats, out);
  } else {
    // fallback: round-1 path (dense re-sweeps), needs only 128 KB
    float* u = (float*)d_ws;
    float* v = u + (size_t)BB * MM;
    init_v_kernel<<<(BB * NN + 255) / 256, 256, 0, stream>>>(v);
    for (int it = 0; it < 3; ++it) {
      u_update_kernel<<<BB * MM / 4, 256, 0, stream>>>(sloc, tloc, smask, tmask, v, u);
      v_update_kernel<<<BB * NN / 4, 256, 0, stream>>>(sloc, tloc, smask, tmask, u, v);
    }
    output_kernel<<<BB * MM, 256, 0, stream>>>(sloc, tloc, smask, tmask, u, v, feats, out);
  }
}